// Round 2
// baseline (620.365 us; speedup 1.0000x reference)
//
#include <hip/hip_runtime.h>
#include <hip/hip_bf16.h>

#define D_IN 128
#define HDIM 128
#define D_E  32
#define NC   16
#define SCAN_CHUNK 2048

typedef __attribute__((ext_vector_type(8))) short short8;
typedef __attribute__((ext_vector_type(4))) float float4v;

__device__ inline short f2bs(float f) {
  __hip_bfloat16 h = (__hip_bfloat16)f;
  return *reinterpret_cast<short*>(&h);
}

__device__ inline float bs2f(short s) {
  unsigned int u = ((unsigned int)(unsigned short)s) << 16;
  float f;
  __builtin_memcpy(&f, &u, 4);
  return f;
}

// ---------------- prologue: degree, CSR ----------------

__global__ __launch_bounds__(256) void count_deg(const int* __restrict__ ei, int* __restrict__ deg, int E) {
  int e = blockIdx.x * 256 + threadIdx.x;
  if (e < E) atomicAdd(&deg[ei[E + e]], 1);
}

__global__ __launch_bounds__(256) void scan_blocksums(const int* __restrict__ deg, int* __restrict__ bsum, int n) {
  __shared__ int red[256];
  int t = threadIdx.x;
  int base = blockIdx.x * SCAN_CHUNK + t * 8;
  int s = 0;
#pragma unroll
  for (int j = 0; j < 8; ++j) {
    int i = base + j;
    if (i < n) s += deg[i];
  }
  red[t] = s;
  __syncthreads();
  for (int off = 128; off > 0; off >>= 1) {
    if (t < off) red[t] += red[t + off];
    __syncthreads();
  }
  if (t == 0) bsum[blockIdx.x] = red[0];
}

__global__ __launch_bounds__(256) void scan_offsets(const int* __restrict__ bsum, int* __restrict__ boff, int nb) {
  __shared__ int s[256];
  int t = threadIdx.x;
  int v = (t < nb) ? bsum[t] : 0;
  s[t] = v;
  __syncthreads();
  for (int off = 1; off < 256; off <<= 1) {
    int u = (t >= off) ? s[t - off] : 0;
    __syncthreads();
    s[t] += u;
    __syncthreads();
  }
  if (t < nb) boff[t] = (t == 0) ? 0 : s[t - 1];
}

__global__ __launch_bounds__(256) void scan_write(const int* __restrict__ deg, const int* __restrict__ boff,
                                                  int* __restrict__ rowptr, float* __restrict__ dinv, int n) {
  __shared__ int red[256];
  int t = threadIdx.x;
  int base = blockIdx.x * SCAN_CHUNK + t * 8;
  int v[8];
  int s = 0;
#pragma unroll
  for (int j = 0; j < 8; ++j) {
    int i = base + j;
    v[j] = (i < n) ? deg[i] : 0;
    s += v[j];
  }
  red[t] = s;
  __syncthreads();
  for (int off = 1; off < 256; off <<= 1) {
    int u = (t >= off) ? red[t - off] : 0;
    __syncthreads();
    red[t] += u;
    __syncthreads();
  }
  int run = red[t] - s + boff[blockIdx.x];
#pragma unroll
  for (int j = 0; j < 8; ++j) {
    int i = base + j;
    if (i < n) {
      rowptr[i] = run;
      dinv[i] = rsqrtf((float)v[j] + 1.0f);
    }
    run += v[j];
  }
}

__global__ __launch_bounds__(256) void fill_csr(const int* __restrict__ ei, const int* __restrict__ rowptr,
                                                int* __restrict__ cursor, int* __restrict__ col, int E) {
  int e = blockIdx.x * 256 + threadIdx.x;
  if (e < E) {
    int d = ei[E + e];
    int pos = atomicAdd(&cursor[d], 1);
    col[rowptr[d] + pos] = ei[e];
  }
}

// ---------------- weight repack into MFMA B-fragment order (bf16) ----------------
__global__ __launch_bounds__(256) void repack_w128(const float* __restrict__ W, short* __restrict__ wp) {
  int idx = blockIdx.x * 256 + threadIdx.x;  // 4*8*64*8 = 16384
  if (idx < 16384) {
    int j = idx & 7, lane = (idx >> 3) & 63, t = (idx >> 9) & 7, kc = idx >> 12;
    int k = kc * 32 + (lane >> 4) * 8 + j;
    int nn = t * 16 + (lane & 15);
    wp[idx] = f2bs(W[k * HDIM + nn]);
  }
}

__global__ __launch_bounds__(256) void repack_wcp(const float* __restrict__ Wfc, short* __restrict__ wp) {
  int idx = blockIdx.x * 256 + threadIdx.x;  // 4*2*64*8 = 4096
  if (idx < 4096) {
    int j = idx & 7, lane = (idx >> 3) & 63, t = (idx >> 9) & 1, kc = idx >> 10;
    int k = kc * 32 + (lane >> 4) * 8 + j;
    int nn = t * 16 + (lane & 15);
    float v = (nn < 16) ? Wfc[k * NC + nn] : Wfc[(HDIM + k) * NC + (nn - 16)];
    wp[idx] = f2bs(v);
  }
}

// Pack Wfc rows 256..287 (edge_attr block), K=32, 16 cols: wp[lane*8+j] = Wfc[256 + (lane>>4)*8+j][lane&15]
__global__ __launch_bounds__(256) void repack_wea(const float* __restrict__ Wfc, short* __restrict__ wp) {
  int idx = blockIdx.x * 256 + threadIdx.x;  // 512
  if (idx < 512) {
    int j = idx & 7, lane = (idx >> 3) & 63;
    int k = (lane >> 4) * 8 + j;
    int nn = lane & 15;
    wp[idx] = f2bs(Wfc[(2 * HDIM + k) * NC + nn]);
  }
}

// ---------------- MFMA GEMM: Y[n x NCOL] = X[n x 128] @ W, K=128 ----------------
// SCALE: multiply output row r by dscale[r] before store (pre-scales messages by dinv).
template<int NCOL, bool FP32IN, bool FP32OUT, bool SCALE>
__global__ __launch_bounds__(256) void gemm_mfma(const void* __restrict__ Xv, const short* __restrict__ wpack,
                                                 void* __restrict__ Yv, const float* __restrict__ dscale, int n) {
  constexpr int NT = NCOL / 16;
  __shared__ short sw[4 * NT * 512];
  int tid = threadIdx.x;
  {
    const float4* wg = (const float4*)wpack;
    float4* sg = (float4*)sw;
    for (int i = tid; i < 4 * NT * 512 / 8; i += 256) sg[i] = wg[i];
  }
  __syncthreads();
  int wave = tid >> 6, lane = tid & 63;
  int quad = lane >> 4;
  int row = blockIdx.x * 64 + wave * 16 + (lane & 15);
  bool rowok = row < n;
  float4v acc[NT];
#pragma unroll
  for (int t = 0; t < NT; ++t) acc[t] = (float4v){0.f, 0.f, 0.f, 0.f};

#pragma unroll
  for (int kc = 0; kc < 4; ++kc) {
    short8 af = {0, 0, 0, 0, 0, 0, 0, 0};
    if (rowok) {
      if (FP32IN) {
        const float* xp = (const float*)Xv + (size_t)row * 128 + kc * 32 + quad * 8;
        float4 x0 = *(const float4*)xp;
        float4 x1 = *(const float4*)(xp + 4);
        af[0] = f2bs(x0.x); af[1] = f2bs(x0.y); af[2] = f2bs(x0.z); af[3] = f2bs(x0.w);
        af[4] = f2bs(x1.x); af[5] = f2bs(x1.y); af[6] = f2bs(x1.z); af[7] = f2bs(x1.w);
      } else {
        af = *(const short8*)((const short*)Xv + (size_t)row * 128 + kc * 32 + quad * 8);
      }
    }
#pragma unroll
    for (int t = 0; t < NT; ++t) {
      short8 bfr = *(const short8*)(sw + (kc * NT + t) * 512 + lane * 8);
      acc[t] = __builtin_amdgcn_mfma_f32_16x16x32_bf16(af, bfr, acc[t], 0, 0, 0);
    }
  }
  // C/D layout: col = lane&15, row = quad*4 + reg
  int orow0 = blockIdx.x * 64 + wave * 16 + quad * 4;
  float dv[4] = {1.f, 1.f, 1.f, 1.f};
  if constexpr (SCALE) {
#pragma unroll
    for (int r = 0; r < 4; ++r) dv[r] = (orow0 + r < n) ? dscale[orow0 + r] : 0.f;
  }
#pragma unroll
  for (int t = 0; t < NT; ++t) {
    int ocol = t * 16 + (lane & 15);
#pragma unroll
    for (int r = 0; r < 4; ++r) {
      int orow = orow0 + r;
      if (orow < n) {
        float val = acc[t][r];
        if constexpr (SCALE) val *= dv[r];
        if (FP32OUT)
          ((float*)Yv)[(size_t)orow * NCOL + ocol] = val;
        else
          ((__hip_bfloat16*)Yv)[(size_t)orow * NCOL + ocol] = (__hip_bfloat16)val;
      }
    }
  }
}

// ---------------- edge-attr GEMM: EA[E x 16] = ea[E x 32] @ Wfc[256:288,:] + bfc, bf16 out ----------------
__global__ __launch_bounds__(256) void gemm_ea(const float* __restrict__ ea, const short* __restrict__ wp,
                                               const float* __restrict__ bfc, __hip_bfloat16* __restrict__ EA, int E) {
  __shared__ short sw[512];
  __shared__ float sb[16];
  int tid = threadIdx.x;
  if (tid < 64) ((float4*)sw)[tid] = ((const float4*)wp)[tid];
  if (tid < 16) sb[tid] = bfc[tid];
  __syncthreads();
  int wave = tid >> 6, lane = tid & 63, quad = lane >> 4;
  int row = blockIdx.x * 64 + wave * 16 + (lane & 15);
  short8 af = {0, 0, 0, 0, 0, 0, 0, 0};
  if (row < E) {
    const float* xp = ea + (size_t)row * D_E + quad * 8;
    float4 x0 = *(const float4*)xp;
    float4 x1 = *(const float4*)(xp + 4);
    af[0] = f2bs(x0.x); af[1] = f2bs(x0.y); af[2] = f2bs(x0.z); af[3] = f2bs(x0.w);
    af[4] = f2bs(x1.x); af[5] = f2bs(x1.y); af[6] = f2bs(x1.z); af[7] = f2bs(x1.w);
  }
  short8 bfr = *(const short8*)(sw + lane * 8);
  float4v acc = (float4v){0.f, 0.f, 0.f, 0.f};
  acc = __builtin_amdgcn_mfma_f32_16x16x32_bf16(af, bfr, acc, 0, 0, 0);
  int orow0 = blockIdx.x * 64 + wave * 16 + quad * 4;
  int ocol = lane & 15;
  float bb = sb[ocol];
#pragma unroll
  for (int r = 0; r < 4; ++r) {
    int orow = orow0 + r;
    if (orow < E) EA[(size_t)orow * NC + ocol] = (__hip_bfloat16)(acc[r] + bb);
  }
}

// ---------------- aggregation over pre-scaled rows hs = (h@W)*dinv ----------------
// 256 thr = 4 waves; each 16-lane quarter owns one node; lane covers 8 features (short8 = 16B).
// 4-deep software pipeline on the col[] index chain.
__global__ __launch_bounds__(256) void agg_vec(const __hip_bfloat16* __restrict__ hs, const float* __restrict__ dinv,
                                               const int* __restrict__ rowptr, const int* __restrict__ deg,
                                               const int* __restrict__ col, const float* __restrict__ bias,
                                               __hip_bfloat16* __restrict__ hout, int N) {
  int tid = threadIdx.x;
  int wave = tid >> 6, lane = tid & 63;
  int q = lane >> 4, ft = lane & 15;
  int i = blockIdx.x * 16 + wave * 4 + q;
  bool ok = i < N;
  int iS = ok ? i : (N - 1);
  int s0 = rowptr[iS];
  int dg = ok ? deg[iS] : 0;
  float di = dinv[iS];
  const short* hb = (const short*)hs;
  short8 selfv = *(const short8*)(hb + (size_t)iS * 128 + ft * 8);
  float acc[8];
#pragma unroll
  for (int j = 0; j < 8; ++j) acc[j] = bs2f(selfv[j]);
  int mx = dg;
  mx = max(mx, __shfl_xor(mx, 16));
  mx = max(mx, __shfl_xor(mx, 32));
  int cA = 0, cB = 0, cC = 0, cD = 0;
  if (0 < dg) cA = col[s0];
  if (1 < dg) cB = col[s0 + 1];
  if (2 < dg) cC = col[s0 + 2];
  if (3 < dg) cD = col[s0 + 3];
  for (int it = 0; it < mx; it += 4) {
    int nA = 0, nB = 0, nC = 0, nD = 0;
    if (it + 4 < dg) nA = col[s0 + it + 4];
    if (it + 5 < dg) nB = col[s0 + it + 5];
    if (it + 6 < dg) nC = col[s0 + it + 6];
    if (it + 7 < dg) nD = col[s0 + it + 7];
    if (it < dg) {
      short8 r0 = *(const short8*)(hb + (size_t)cA * 128 + ft * 8);
#pragma unroll
      for (int j = 0; j < 8; ++j) acc[j] += bs2f(r0[j]);
    }
    if (it + 1 < dg) {
      short8 r1 = *(const short8*)(hb + (size_t)cB * 128 + ft * 8);
#pragma unroll
      for (int j = 0; j < 8; ++j) acc[j] += bs2f(r1[j]);
    }
    if (it + 2 < dg) {
      short8 r2 = *(const short8*)(hb + (size_t)cC * 128 + ft * 8);
#pragma unroll
      for (int j = 0; j < 8; ++j) acc[j] += bs2f(r2[j]);
    }
    if (it + 3 < dg) {
      short8 r3 = *(const short8*)(hb + (size_t)cD * 128 + ft * 8);
#pragma unroll
      for (int j = 0; j < 8; ++j) acc[j] += bs2f(r3[j]);
    }
    cA = nA; cB = nB; cC = nC; cD = nD;
  }
  if (ok) {
    float4 b0 = *(const float4*)(bias + ft * 8);
    float4 b1 = *(const float4*)(bias + ft * 8 + 4);
    float bb[8] = {b0.x, b0.y, b0.z, b0.w, b1.x, b1.y, b1.z, b1.w};
    short8 o;
#pragma unroll
    for (int j = 0; j < 8; ++j) {
      float v = fmaxf(fmaf(acc[j], di, bb[j]), 0.f);
      o[j] = f2bs(v);
    }
    *(short8*)((short*)hout + (size_t)i * 128 + ft * 8) = o;
  }
}

// ---------------- final edge head: l = PQ[s][0:16] + PQ[d][16:32] + EA[e]; log-softmax ----------------
__global__ __launch_bounds__(256) void edge_final(const int* __restrict__ ei, const __hip_bfloat16* __restrict__ EA,
                                                  const float* __restrict__ PQ, float* __restrict__ out, int E) {
  int e = blockIdx.x * 256 + threadIdx.x;
  bool ok = e < E;
  int ec = ok ? e : (E - 1);
  int s = ei[ec], d = ei[E + ec];
  const float4* p1 = (const float4*)(PQ + (size_t)s * 32);
  const float4* p2 = (const float4*)(PQ + (size_t)d * 32 + 16);
  const short* eb = (const short*)EA + (size_t)ec * NC;
  short8 ev0 = *(const short8*)eb;
  short8 ev1 = *(const short8*)(eb + 8);
  float l[NC];
  float4 P0 = p1[0], P1 = p1[1], P2 = p1[2], P3 = p1[3];
  float4 Q0 = p2[0], Q1 = p2[1], Q2 = p2[2], Q3 = p2[3];
  l[0]  = P0.x + Q0.x + bs2f(ev0[0]);
  l[1]  = P0.y + Q0.y + bs2f(ev0[1]);
  l[2]  = P0.z + Q0.z + bs2f(ev0[2]);
  l[3]  = P0.w + Q0.w + bs2f(ev0[3]);
  l[4]  = P1.x + Q1.x + bs2f(ev0[4]);
  l[5]  = P1.y + Q1.y + bs2f(ev0[5]);
  l[6]  = P1.z + Q1.z + bs2f(ev0[6]);
  l[7]  = P1.w + Q1.w + bs2f(ev0[7]);
  l[8]  = P2.x + Q2.x + bs2f(ev1[0]);
  l[9]  = P2.y + Q2.y + bs2f(ev1[1]);
  l[10] = P2.z + Q2.z + bs2f(ev1[2]);
  l[11] = P2.w + Q2.w + bs2f(ev1[3]);
  l[12] = P3.x + Q3.x + bs2f(ev1[4]);
  l[13] = P3.y + Q3.y + bs2f(ev1[5]);
  l[14] = P3.z + Q3.z + bs2f(ev1[6]);
  l[15] = P3.w + Q3.w + bs2f(ev1[7]);
  float m = l[0];
#pragma unroll
  for (int c = 1; c < NC; ++c) m = fmaxf(m, l[c]);
  float sum = 0.f;
#pragma unroll
  for (int c = 0; c < NC; ++c) sum += __expf(l[c] - m);
  float lse = __logf(sum) + m;
  if (ok) {
    float4* po = (float4*)(out + (size_t)e * NC);
    po[0] = make_float4(l[0] - lse, l[1] - lse, l[2] - lse, l[3] - lse);
    po[1] = make_float4(l[4] - lse, l[5] - lse, l[6] - lse, l[7] - lse);
    po[2] = make_float4(l[8] - lse, l[9] - lse, l[10] - lse, l[11] - lse);
    po[3] = make_float4(l[12] - lse, l[13] - lse, l[14] - lse, l[15] - lse);
  }
}

// ---------------- launch ----------------

extern "C" void kernel_launch(void* const* d_in, const int* in_sizes, int n_in,
                              void* d_out, int out_size, void* d_ws, size_t ws_size,
                              hipStream_t stream) {
  const float* x   = (const float*)d_in[0];
  const int*   ei  = (const int*)d_in[1];
  const float* ea  = (const float*)d_in[2];
  const float* W1  = (const float*)d_in[3];
  const float* b1  = (const float*)d_in[4];
  const float* W2  = (const float*)d_in[5];
  const float* b2  = (const float*)d_in[6];
  const float* W3  = (const float*)d_in[7];
  const float* b3  = (const float*)d_in[8];
  const float* Wfc = (const float*)d_in[9];
  const float* bfc = (const float*)d_in[10];
  float* out = (float*)d_out;
  int N = in_sizes[0] / D_IN;
  int E = in_sizes[1] / 2;

  char* w = (char*)d_ws;
  size_t off = 0;
  auto alloc = [&](size_t bytes) -> char* {
    char* p = w + off;
    off += (bytes + 255) & ~(size_t)255;
    return p;
  };
  __hip_bfloat16* A = (__hip_bfloat16*)alloc((size_t)N * HDIM * 2);  // 25.6 MB
  __hip_bfloat16* B = (__hip_bfloat16*)alloc((size_t)N * HDIM * 2);  // 25.6 MB
  float* PQ     = (float*)alloc((size_t)N * 32 * 4);                 // 12.8 MB
  __hip_bfloat16* EA = (__hip_bfloat16*)alloc((size_t)E * NC * 2);   // 32 MB
  int*   col    = (int*)alloc((size_t)E * 4);
  int*   deg    = (int*)alloc((size_t)N * 4);
  int*   cursor = (int*)alloc((size_t)N * 4);
  float* dinv   = (float*)alloc((size_t)N * 4);
  int*   rowptr = (int*)alloc((size_t)N * 4);
  int*   bsum   = (int*)alloc(1024 * 4);
  int*   boff   = (int*)alloc(1024 * 4);
  short* wp1    = (short*)alloc(16384 * 2);
  short* wp2    = (short*)alloc(16384 * 2);
  short* wp3    = (short*)alloc(16384 * 2);
  short* wpc    = (short*)alloc(4096 * 2);
  short* wpe    = (short*)alloc(512 * 2);

  hipMemsetAsync(deg, 0, (size_t)N * 4, stream);
  hipMemsetAsync(cursor, 0, (size_t)N * 4, stream);

  int eb = (E + 255) / 256;
  int sb = (N + SCAN_CHUNK - 1) / SCAN_CHUNK;
  count_deg<<<eb, 256, 0, stream>>>(ei, deg, E);
  scan_blocksums<<<sb, 256, 0, stream>>>(deg, bsum, N);
  scan_offsets<<<1, 256, 0, stream>>>(bsum, boff, sb);
  scan_write<<<sb, 256, 0, stream>>>(deg, boff, rowptr, dinv, N);
  fill_csr<<<eb, 256, 0, stream>>>(ei, rowptr, cursor, col, E);
  repack_w128<<<64, 256, 0, stream>>>(W1, wp1);
  repack_w128<<<64, 256, 0, stream>>>(W2, wp2);
  repack_w128<<<64, 256, 0, stream>>>(W3, wp3);
  repack_wcp<<<16, 256, 0, stream>>>(Wfc, wpc);
  repack_wea<<<2, 256, 0, stream>>>(Wfc, wpe);

  int gb = (N + 63) / 64;
  int ab = (N + 15) / 16;
  int geb = (E + 63) / 64;
  gemm_ea<<<geb, 256, 0, stream>>>(ea, wpe, bfc, EA, E);
  gemm_mfma<128, true,  false, true ><<<gb, 256, 0, stream>>>(x, wp1, A, dinv, N);
  agg_vec<<<ab, 256, 0, stream>>>(A, dinv, rowptr, deg, col, b1, B, N);
  gemm_mfma<128, false, false, true ><<<gb, 256, 0, stream>>>(B, wp2, A, dinv, N);
  agg_vec<<<ab, 256, 0, stream>>>(A, dinv, rowptr, deg, col, b2, B, N);
  gemm_mfma<128, false, false, true ><<<gb, 256, 0, stream>>>(B, wp3, A, dinv, N);
  agg_vec<<<ab, 256, 0, stream>>>(A, dinv, rowptr, deg, col, b3, B, N);
  gemm_mfma<32,  false, true,  false><<<gb, 256, 0, stream>>>(B, wpc, PQ, nullptr, N);
  edge_final<<<eb, 256, 0, stream>>>(ei, EA, PQ, out, E);
}

// Round 4
// 581.405 us; speedup vs baseline: 1.0670x; 1.0670x over previous
//
#include <hip/hip_runtime.h>
#include <hip/hip_bf16.h>

#define D_IN 128
#define HDIM 128
#define D_E  32
#define NC   16
#define SCAN_CHUNK 2048

typedef __attribute__((ext_vector_type(8))) short short8;
typedef __attribute__((ext_vector_type(4))) float float4v;

__device__ inline short f2bs(float f) {
  __hip_bfloat16 h = (__hip_bfloat16)f;
  return *reinterpret_cast<short*>(&h);
}

__device__ inline float bs2f(short s) {
  unsigned int u = ((unsigned int)(unsigned short)s) << 16;
  float f;
  __builtin_memcpy(&f, &u, 4);
  return f;
}

// ---------------- prologue: degree, CSR ----------------

__global__ __launch_bounds__(256) void count_deg(const int* __restrict__ ei, int* __restrict__ deg, int E) {
  int e = blockIdx.x * 256 + threadIdx.x;
  if (e < E) atomicAdd(&deg[ei[E + e]], 1);
}

__global__ __launch_bounds__(256) void scan_blocksums(const int* __restrict__ deg, int* __restrict__ bsum, int n) {
  __shared__ int red[256];
  int t = threadIdx.x;
  int base = blockIdx.x * SCAN_CHUNK + t * 8;
  int s = 0;
#pragma unroll
  for (int j = 0; j < 8; ++j) {
    int i = base + j;
    if (i < n) s += deg[i];
  }
  red[t] = s;
  __syncthreads();
  for (int off = 128; off > 0; off >>= 1) {
    if (t < off) red[t] += red[t + off];
    __syncthreads();
  }
  if (t == 0) bsum[blockIdx.x] = red[0];
}

__global__ __launch_bounds__(256) void scan_offsets(const int* __restrict__ bsum, int* __restrict__ boff, int nb) {
  __shared__ int s[256];
  int t = threadIdx.x;
  int v = (t < nb) ? bsum[t] : 0;
  s[t] = v;
  __syncthreads();
  for (int off = 1; off < 256; off <<= 1) {
    int u = (t >= off) ? s[t - off] : 0;
    __syncthreads();
    s[t] += u;
    __syncthreads();
  }
  if (t < nb) boff[t] = (t == 0) ? 0 : s[t - 1];
}

__global__ __launch_bounds__(256) void scan_write(const int* __restrict__ deg, const int* __restrict__ boff,
                                                  int* __restrict__ rowptr, float* __restrict__ dinv, int n) {
  __shared__ int red[256];
  int t = threadIdx.x;
  int base = blockIdx.x * SCAN_CHUNK + t * 8;
  int v[8];
  int s = 0;
#pragma unroll
  for (int j = 0; j < 8; ++j) {
    int i = base + j;
    v[j] = (i < n) ? deg[i] : 0;
    s += v[j];
  }
  red[t] = s;
  __syncthreads();
  for (int off = 1; off < 256; off <<= 1) {
    int u = (t >= off) ? red[t - off] : 0;
    __syncthreads();
    red[t] += u;
    __syncthreads();
  }
  int run = red[t] - s + boff[blockIdx.x];
#pragma unroll
  for (int j = 0; j < 8; ++j) {
    int i = base + j;
    if (i < n) {
      rowptr[i] = run;
      dinv[i] = rsqrtf((float)v[j] + 1.0f);
    }
    run += v[j];
  }
}

__global__ __launch_bounds__(256) void fill_csr(const int* __restrict__ ei, const int* __restrict__ rowptr,
                                                int* __restrict__ cursor, int* __restrict__ col, int E) {
  int e = blockIdx.x * 256 + threadIdx.x;
  if (e < E) {
    int d = ei[E + e];
    int pos = atomicAdd(&cursor[d], 1);
    col[rowptr[d] + pos] = ei[e];
  }
}

// ---------------- weight repack into MFMA B-fragment order (bf16) ----------------
__global__ __launch_bounds__(256) void repack_w128(const float* __restrict__ W, short* __restrict__ wp) {
  int idx = blockIdx.x * 256 + threadIdx.x;  // 4*8*64*8 = 16384
  if (idx < 16384) {
    int j = idx & 7, lane = (idx >> 3) & 63, t = (idx >> 9) & 7, kc = idx >> 12;
    int k = kc * 32 + (lane >> 4) * 8 + j;
    int nn = t * 16 + (lane & 15);
    wp[idx] = f2bs(W[k * HDIM + nn]);
  }
}

__global__ __launch_bounds__(256) void repack_wcp(const float* __restrict__ Wfc, short* __restrict__ wp) {
  int idx = blockIdx.x * 256 + threadIdx.x;  // 4*2*64*8 = 4096
  if (idx < 4096) {
    int j = idx & 7, lane = (idx >> 3) & 63, t = (idx >> 9) & 1, kc = idx >> 10;
    int k = kc * 32 + (lane >> 4) * 8 + j;
    int nn = t * 16 + (lane & 15);
    float v = (nn < 16) ? Wfc[k * NC + nn] : Wfc[(HDIM + k) * NC + (nn - 16)];
    wp[idx] = f2bs(v);
  }
}

// Pack Wfc rows 256..287 (edge_attr block), K=32, 16 cols: wp[lane*8+j] = Wfc[256 + (lane>>4)*8+j][lane&15]
__global__ __launch_bounds__(256) void repack_wea(const float* __restrict__ Wfc, short* __restrict__ wp) {
  int idx = blockIdx.x * 256 + threadIdx.x;  // 512
  if (idx < 512) {
    int j = idx & 7, lane = (idx >> 3) & 63;
    int k = (lane >> 4) * 8 + j;
    int nn = lane & 15;
    wp[idx] = f2bs(Wfc[(2 * HDIM + k) * NC + nn]);
  }
}

// ---------------- MFMA GEMM: Y[n x NCOL] = X[n x 128] @ W, K=128 ----------------
// SCALE: multiply output row r by dscale[r] before store (pre-scales messages by dinv).
template<int NCOL, bool FP32IN, bool FP32OUT, bool SCALE>
__global__ __launch_bounds__(256) void gemm_mfma(const void* __restrict__ Xv, const short* __restrict__ wpack,
                                                 void* __restrict__ Yv, const float* __restrict__ dscale, int n) {
  constexpr int NT = NCOL / 16;
  __shared__ short sw[4 * NT * 512];
  int tid = threadIdx.x;
  {
    const float4* wg = (const float4*)wpack;
    float4* sg = (float4*)sw;
    for (int i = tid; i < 4 * NT * 512 / 8; i += 256) sg[i] = wg[i];
  }
  __syncthreads();
  int wave = tid >> 6, lane = tid & 63;
  int quad = lane >> 4;
  int row = blockIdx.x * 64 + wave * 16 + (lane & 15);
  bool rowok = row < n;
  float4v acc[NT];
#pragma unroll
  for (int t = 0; t < NT; ++t) acc[t] = (float4v){0.f, 0.f, 0.f, 0.f};

#pragma unroll
  for (int kc = 0; kc < 4; ++kc) {
    short8 af = {0, 0, 0, 0, 0, 0, 0, 0};
    if (rowok) {
      if (FP32IN) {
        const float* xp = (const float*)Xv + (size_t)row * 128 + kc * 32 + quad * 8;
        float4 x0 = *(const float4*)xp;
        float4 x1 = *(const float4*)(xp + 4);
        af[0] = f2bs(x0.x); af[1] = f2bs(x0.y); af[2] = f2bs(x0.z); af[3] = f2bs(x0.w);
        af[4] = f2bs(x1.x); af[5] = f2bs(x1.y); af[6] = f2bs(x1.z); af[7] = f2bs(x1.w);
      } else {
        af = *(const short8*)((const short*)Xv + (size_t)row * 128 + kc * 32 + quad * 8);
      }
    }
#pragma unroll
    for (int t = 0; t < NT; ++t) {
      short8 bfr = *(const short8*)(sw + (kc * NT + t) * 512 + lane * 8);
      acc[t] = __builtin_amdgcn_mfma_f32_16x16x32_bf16(af, bfr, acc[t], 0, 0, 0);
    }
  }
  // C/D layout: col = lane&15, row = quad*4 + reg
  int orow0 = blockIdx.x * 64 + wave * 16 + quad * 4;
  float dv[4] = {1.f, 1.f, 1.f, 1.f};
  if constexpr (SCALE) {
#pragma unroll
    for (int r = 0; r < 4; ++r) dv[r] = (orow0 + r < n) ? dscale[orow0 + r] : 0.f;
  }
#pragma unroll
  for (int t = 0; t < NT; ++t) {
    int ocol = t * 16 + (lane & 15);
#pragma unroll
    for (int r = 0; r < 4; ++r) {
      int orow = orow0 + r;
      if (orow < n) {
        float val = acc[t][r];
        if constexpr (SCALE) val *= dv[r];
        if (FP32OUT)
          ((float*)Yv)[(size_t)orow * NCOL + ocol] = val;
        else
          ((__hip_bfloat16*)Yv)[(size_t)orow * NCOL + ocol] = (__hip_bfloat16)val;
      }
    }
  }
}

// ---------------- aggregation over pre-scaled rows hs = (h@W)*dinv ----------------
// 256 thr = 4 waves; each 16-lane quarter owns one node; lane covers 8 features (short8 = 16B).
// Batch-16 index fetch: the quad's 16 lanes cooperatively load 16 neighbor indices in ONE
// coalesced instruction, then 16 unrolled {shfl idx -> 16B row gather -> accumulate} slots.
// All 16 gathers issue after one index-load latency -> up to 64 outstanding gathers/wave.
// NOTE: shuffles only read lanes within the same quad; dg/rem are quad-uniform, so the
// shuffle sources always executed the same iteration (divergence across quads is safe).
__global__ __launch_bounds__(256) void agg_vec(const __hip_bfloat16* __restrict__ hs, const float* __restrict__ dinv,
                                               const int* __restrict__ rowptr, const int* __restrict__ deg,
                                               const int* __restrict__ col, const float* __restrict__ bias,
                                               __hip_bfloat16* __restrict__ hout, int N) {
  int tid = threadIdx.x;
  int wave = tid >> 6, lane = tid & 63;
  int q = lane >> 4, ft = lane & 15;
  int i = blockIdx.x * 16 + wave * 4 + q;
  bool ok = i < N;
  int iS = ok ? i : (N - 1);
  int s0 = rowptr[iS];
  int dg = ok ? deg[iS] : 0;
  float di = dinv[iS];
  const short* hb = (const short*)hs;
  short8 selfv = *(const short8*)(hb + (size_t)iS * 128 + ft * 8);
  float acc[8];
#pragma unroll
  for (int j = 0; j < 8; ++j) acc[j] = bs2f(selfv[j]);
  for (int b = 0; b < dg; b += 16) {
    int rem = dg - b;
    int myidx = (ft < rem) ? col[s0 + b + ft] : 0;
#pragma unroll
    for (int k = 0; k < 16; ++k) {
      if (k < rem) {
        int ck = __shfl(myidx, (q << 4) + k);
        short8 r = *(const short8*)(hb + (size_t)ck * 128 + ft * 8);
#pragma unroll
        for (int j = 0; j < 8; ++j) acc[j] += bs2f(r[j]);
      }
    }
  }
  if (ok) {
    float4 b0 = *(const float4*)(bias + ft * 8);
    float4 b1 = *(const float4*)(bias + ft * 8 + 4);
    float bb[8] = {b0.x, b0.y, b0.z, b0.w, b1.x, b1.y, b1.z, b1.w};
    short8 o;
#pragma unroll
    for (int j = 0; j < 8; ++j) {
      float v = fmaxf(fmaf(acc[j], di, bb[j]), 0.f);
      o[j] = f2bs(v);
    }
    *(short8*)((short*)hout + (size_t)i * 128 + ft * 8) = o;
  }
}

// ---------------- fused edge head: MFMA ea@We, + PQ[s] + PQ[d] + b, quad-shuffle log-softmax ----------------
// MFMA C-layout: row j's 16 class logits live in the 16 lanes of quad (j>>2), reg (j&3).
// Softmax over classes = 4x shfl_xor within the quad. No LDS staging of edges, no EA intermediate.
__global__ __launch_bounds__(256) void edge_fused(const int* __restrict__ ei, const float* __restrict__ ea,
                                                  const short* __restrict__ wpe, const float* __restrict__ bfc,
                                                  const float* __restrict__ PQ, float* __restrict__ out, int E) {
  __shared__ short sw[512];
  __shared__ float sb[16];
  int tid = threadIdx.x;
  if (tid < 64) ((float4*)sw)[tid] = ((const float4*)wpe)[tid];
  if (tid < 16) sb[tid] = bfc[tid];
  __syncthreads();
  int wave = tid >> 6, lane = tid & 63, quad = lane >> 4;
  int row = blockIdx.x * 64 + wave * 16 + (lane & 15);
  short8 af = {0, 0, 0, 0, 0, 0, 0, 0};
  if (row < E) {
    const float* xp = ea + (size_t)row * D_E + quad * 8;
    float4 x0 = *(const float4*)xp;
    float4 x1 = *(const float4*)(xp + 4);
    af[0] = f2bs(x0.x); af[1] = f2bs(x0.y); af[2] = f2bs(x0.z); af[3] = f2bs(x0.w);
    af[4] = f2bs(x1.x); af[5] = f2bs(x1.y); af[6] = f2bs(x1.z); af[7] = f2bs(x1.w);
  }
  short8 bfr = *(const short8*)(sw + lane * 8);
  float4v acc = (float4v){0.f, 0.f, 0.f, 0.f};
  acc = __builtin_amdgcn_mfma_f32_16x16x32_bf16(af, bfr, acc, 0, 0, 0);
  int c = lane & 15;
  int orow0 = blockIdx.x * 64 + wave * 16 + quad * 4;
  float bb = sb[c];
  // hoist all PQ gathers (quad-coalesced 64B segments) ahead of the softmax chain
  float ps[4], pd[4];
#pragma unroll
  for (int r = 0; r < 4; ++r) {
    int orow = orow0 + r;
    int er = (orow < E) ? orow : (E - 1);
    int s = ei[er], d = ei[E + er];
    ps[r] = PQ[(size_t)s * 32 + c];
    pd[r] = PQ[(size_t)d * 32 + 16 + c];
  }
#pragma unroll
  for (int r = 0; r < 4; ++r) {
    float l = acc[r] + bb + ps[r] + pd[r];
    float m = l;
#pragma unroll
    for (int w = 1; w < 16; w <<= 1) m = fmaxf(m, __shfl_xor(m, w));
    float ex = __expf(l - m);
    float sum = ex;
#pragma unroll
    for (int w = 1; w < 16; w <<= 1) sum += __shfl_xor(sum, w);
    float lse = __logf(sum) + m;
    int orow = orow0 + r;
    if (orow < E) out[(size_t)orow * NC + c] = l - lse;
  }
}

// ---------------- launch ----------------

extern "C" void kernel_launch(void* const* d_in, const int* in_sizes, int n_in,
                              void* d_out, int out_size, void* d_ws, size_t ws_size,
                              hipStream_t stream) {
  const float* x   = (const float*)d_in[0];
  const int*   ei  = (const int*)d_in[1];
  const float* ea  = (const float*)d_in[2];
  const float* W1  = (const float*)d_in[3];
  const float* b1  = (const float*)d_in[4];
  const float* W2  = (const float*)d_in[5];
  const float* b2  = (const float*)d_in[6];
  const float* W3  = (const float*)d_in[7];
  const float* b3  = (const float*)d_in[8];
  const float* Wfc = (const float*)d_in[9];
  const float* bfc = (const float*)d_in[10];
  float* out = (float*)d_out;
  int N = in_sizes[0] / D_IN;
  int E = in_sizes[1] / 2;

  char* w = (char*)d_ws;
  size_t off = 0;
  auto alloc = [&](size_t bytes) -> char* {
    char* p = w + off;
    off += (bytes + 255) & ~(size_t)255;
    return p;
  };
  __hip_bfloat16* A = (__hip_bfloat16*)alloc((size_t)N * HDIM * 2);  // 25.6 MB
  __hip_bfloat16* B = (__hip_bfloat16*)alloc((size_t)N * HDIM * 2);  // 25.6 MB
  float* PQ     = (float*)alloc((size_t)N * 32 * 4);                 // 12.8 MB
  int*   col    = (int*)alloc((size_t)E * 4);
  int*   deg    = (int*)alloc((size_t)N * 4);
  int*   cursor = (int*)alloc((size_t)N * 4);
  float* dinv   = (float*)alloc((size_t)N * 4);
  int*   rowptr = (int*)alloc((size_t)N * 4);
  int*   bsum   = (int*)alloc(1024 * 4);
  int*   boff   = (int*)alloc(1024 * 4);
  short* wp1    = (short*)alloc(16384 * 2);
  short* wp2    = (short*)alloc(16384 * 2);
  short* wp3    = (short*)alloc(16384 * 2);
  short* wpc    = (short*)alloc(4096 * 2);
  short* wpe    = (short*)alloc(512 * 2);

  hipMemsetAsync(deg, 0, (size_t)N * 4, stream);
  hipMemsetAsync(cursor, 0, (size_t)N * 4, stream);

  int eb = (E + 255) / 256;
  int sb = (N + SCAN_CHUNK - 1) / SCAN_CHUNK;
  count_deg<<<eb, 256, 0, stream>>>(ei, deg, E);
  scan_blocksums<<<sb, 256, 0, stream>>>(deg, bsum, N);
  scan_offsets<<<1, 256, 0, stream>>>(bsum, boff, sb);
  scan_write<<<sb, 256, 0, stream>>>(deg, boff, rowptr, dinv, N);
  fill_csr<<<eb, 256, 0, stream>>>(ei, rowptr, cursor, col, E);
  repack_w128<<<64, 256, 0, stream>>>(W1, wp1);
  repack_w128<<<64, 256, 0, stream>>>(W2, wp2);
  repack_w128<<<64, 256, 0, stream>>>(W3, wp3);
  repack_wcp<<<16, 256, 0, stream>>>(Wfc, wpc);
  repack_wea<<<2, 256, 0, stream>>>(Wfc, wpe);

  int gb = (N + 63) / 64;
  int ab = (N + 15) / 16;
  int geb = (E + 63) / 64;
  gemm_mfma<128, true,  false, true ><<<gb, 256, 0, stream>>>(x, wp1, A, dinv, N);
  agg_vec<<<ab, 256, 0, stream>>>(A, dinv, rowptr, deg, col, b1, B, N);
  gemm_mfma<128, false, false, true ><<<gb, 256, 0, stream>>>(B, wp2, A, dinv, N);
  agg_vec<<<ab, 256, 0, stream>>>(A, dinv, rowptr, deg, col, b2, B, N);
  gemm_mfma<128, false, false, true ><<<gb, 256, 0, stream>>>(B, wp3, A, dinv, N);
  agg_vec<<<ab, 256, 0, stream>>>(A, dinv, rowptr, deg, col, b3, B, N);
  gemm_mfma<32,  false, true,  false><<<gb, 256, 0, stream>>>(B, wpc, PQ, nullptr, N);
  edge_fused<<<geb, 256, 0, stream>>>(ei, ea, wpe, bfc, PQ, out, E);
}